// Round 10
// baseline (188.929 us; speedup 1.0000x reference)
//
#include <hip/hip_runtime.h>
#include <stdint.h>

#define NH 16
#define NN 4096

typedef __attribute__((ext_vector_type(8))) short bf16x8;
typedef __attribute__((ext_vector_type(4))) short bf16x4;
typedef __attribute__((ext_vector_type(4))) float f32x4;
typedef __attribute__((ext_vector_type(16))) float f32x16;
typedef unsigned short u16;
typedef unsigned int u32;
typedef __attribute__((ext_vector_type(4))) u32 u32x4;

__device__ __forceinline__ u16 f2bf(float f) {
  u32 u = __float_as_uint(f);
  return (u16)((u + 0x7FFFu + ((u >> 16) & 1u)) >> 16);
}

#define GLD16(gp, lp)                                              \
  __builtin_amdgcn_global_load_lds(                                \
      (__attribute__((address_space(1))) void*)(gp),               \
      (__attribute__((address_space(3))) void*)(lp), 16, 0, 0)

// ---------------- elementwise f32 -> bf16 ----------------
__global__ __launch_bounds__(256) void cvt_bf16_kernel(const float* __restrict__ src,
                                                       u16* __restrict__ dst, int n) {
  int i = (blockIdx.x * blockDim.x + threadIdx.x) * 8;
  if (i >= n) return;
  float4 a = *(const float4*)(src + i);
  float4 b = *(const float4*)(src + i + 4);
  uint4 o;
  o.x = (u32)f2bf(a.x) | ((u32)f2bf(a.y) << 16);
  o.y = (u32)f2bf(a.z) | ((u32)f2bf(a.w) << 16);
  o.z = (u32)f2bf(b.x) | ((u32)f2bf(b.y) << 16);
  o.w = (u32)f2bf(b.z) | ((u32)f2bf(b.w) << 16);
  *(uint4*)(dst + i) = o;
}

// ---------------- fused 4x transpose + cvt: W[k][n] f32 -> Wt[n][k] bf16 ----------------
__global__ __launch_bounds__(256) void transpose4(const float* __restrict__ Wq,
                                                  const float* __restrict__ Wk,
                                                  const float* __restrict__ Wv,
                                                  const float* __restrict__ Wo,
                                                  u16* __restrict__ Wqt, u16* __restrict__ Wkt,
                                                  u16* __restrict__ Wvt, u16* __restrict__ Wot) {
  __shared__ float tile[64][65];
  const float* src;
  u16* dst;
  float scale = 1.0f;
  int z = blockIdx.z;
  if (z == 0) { src = Wq; dst = Wqt; scale = 0.125f * 1.4426950408889634f; }
  else if (z == 1) { src = Wk; dst = Wkt; }
  else if (z == 2) { src = Wv; dst = Wvt; }
  else { src = Wo; dst = Wot; }
  int tx = threadIdx.x & 63, ty = threadIdx.x >> 6;
  int c0 = blockIdx.x * 64, r0 = blockIdx.y * 64;
#pragma unroll
  for (int i = ty; i < 64; i += 4)
    tile[i][tx] = src[(size_t)(r0 + i) * 1024 + c0 + tx];
  __syncthreads();
#pragma unroll
  for (int i = ty; i < 64; i += 4)
    dst[(size_t)(c0 + i) * 1024 + r0 + tx] = f2bf(tile[tx][i] * scale);
}

// ---------------- fused QKV GEMM: [4096][1024] @ Wt[3072][1024]^T ----------------
// V (sec==2) is stored with n-within-16 quads interleaved [0,2,1,3] so flash PV
// can read each A-fragment as a single b128.
__global__ __launch_bounds__(256) void gemm_qkv(const u16* __restrict__ A,
                                                const u16* __restrict__ Bt,
                                                u16* __restrict__ Qb, u16* __restrict__ Kb,
                                                u16* __restrict__ Vth) {
  __shared__ __align__(16) u16 A_lds[2][128 * 32];
  __shared__ __align__(16) u16 B_lds[2][128 * 32];
  const int tid = threadIdx.x;
  const int l = tid & 63, w = tid >> 6;
  const int g = l >> 4, c = l & 15;
  const int wr = w >> 1, wc = w & 1;
  const int m0 = blockIdx.y * 128, n0 = blockIdx.x * 128;

  const int srow = tid >> 2;
  const u32 sswz = (u32)(((tid & 3) * 16) ^ ((srow & 3) << 4));
  const char* Ag = (const char*)A + (size_t)(m0 + srow) * 2048 + sswz;
  const char* Bg = (const char*)Bt + (size_t)(n0 + srow) * 2048 + sswz;
  const u32 ldsb = (u32)(w * 1024);

#define GSTAGE(buf, ks_)                                                          \
  do {                                                                            \
    u32 koff_ = (u32)(ks_) * 64;                                                  \
    _Pragma("unroll") for (int p_ = 0; p_ < 2; ++p_) {                            \
      GLD16(Ag + koff_ + (size_t)p_ * 64 * 2048,                                  \
            (char*)A_lds[buf] + p_ * 4096 + ldsb);                                \
      GLD16(Bg + koff_ + (size_t)p_ * 64 * 2048,                                  \
            (char*)B_lds[buf] + p_ * 4096 + ldsb);                                \
    }                                                                             \
  } while (0)

  f32x4 acc[4][4];
#pragma unroll
  for (int i = 0; i < 4; ++i)
#pragma unroll
    for (int j = 0; j < 4; ++j) acc[i][j] = (f32x4){0.f, 0.f, 0.f, 0.f};

  int cur = 0;
  GSTAGE(0, 0);
  for (int ks = 0; ks < 32; ++ks) {
    GSTAGE(cur ^ 1, (ks + 1) & 31);
    asm volatile("s_waitcnt vmcnt(4)" ::: "memory");
    __builtin_amdgcn_s_barrier();
    __builtin_amdgcn_sched_barrier(0);
    const char* Ac = (const char*)A_lds[cur];
    const char* Bc = (const char*)B_lds[cur];
    bf16x8 af[4], bfr[4];
#pragma unroll
    for (int i = 0; i < 4; ++i) {
      int row = wr * 64 + i * 16 + c;
      af[i] = *(const bf16x8*)(Ac + row * 64 + ((g * 16) ^ ((row & 3) << 4)));
    }
#pragma unroll
    for (int j = 0; j < 4; ++j) {
      int row = wc * 64 + j * 16 + c;
      bfr[j] = *(const bf16x8*)(Bc + row * 64 + ((g * 16) ^ ((row & 3) << 4)));
    }
    __builtin_amdgcn_s_setprio(1);
#pragma unroll
    for (int i = 0; i < 4; ++i)
#pragma unroll
      for (int j = 0; j < 4; ++j)
        acc[i][j] = __builtin_amdgcn_mfma_f32_16x16x32_bf16(af[i], bfr[j], acc[i][j], 0, 0, 0);
    __builtin_amdgcn_s_setprio(0);
    asm volatile("s_waitcnt lgkmcnt(0)" ::: "memory");
    __builtin_amdgcn_s_barrier();
    __builtin_amdgcn_sched_barrier(0);
    cur ^= 1;
  }
#undef GSTAGE

  const int sec = n0 >> 10;  // block-uniform: 0=Q, 1=K, 2=V
  const int gq = ((g & 1) << 1) | (g >> 1);  // quad-swap 1<->2 for V n-order
#pragma unroll
  for (int i = 0; i < 4; ++i)
#pragma unroll
    for (int j = 0; j < 4; ++j)
#pragma unroll
      for (int r = 0; r < 4; ++r) {
        int m = m0 + wr * 64 + i * 16 + g * 4 + r;
        int col = n0 + wc * 64 + j * 16 + c;
        int cc = col & 1023;
        u16 v = f2bf(acc[i][j][r]);
        if (sec == 0) Qb[(size_t)m * 1024 + cc] = v;
        else if (sec == 1) Kb[(size_t)m * 1024 + cc] = v;
        else {
          int mq = m0 + wr * 64 + i * 16 + gq * 4 + r;
          Vth[(size_t)cc * 4096 + mq] = v;  // cc = h*64+d, quad-interleaved n
        }
      }
}

// ---------------- out-proj GEMM, 128x64 tiles: out[4096][1024] = A @ Wot^T + bo ----------------
// 4 waves: wave w owns rows [w*32, w*32+32), all 64 cols. 3 GLD16 + 6 ds_read + 8 MFMA / kstep.
__global__ __launch_bounds__(256) void gemm_out128(const u16* __restrict__ A,
                                                   const u16* __restrict__ Bt,
                                                   float* __restrict__ out,
                                                   const float* __restrict__ bias) {
  __shared__ __align__(16) u16 A_lds[2][128 * 32];
  __shared__ __align__(16) u16 B_lds[2][64 * 32];
  const int tid = threadIdx.x;
  const int l = tid & 63, w = tid >> 6;
  const int g = l >> 4, c = l & 15;
  const int m0 = blockIdx.y * 128, n0 = blockIdx.x * 64;

  const int srow = tid >> 2;
  const u32 sswz = (u32)(((tid & 3) * 16) ^ ((srow & 3) << 4));
  const char* Ag = (const char*)A + (size_t)(m0 + srow) * 2048 + sswz;
  const char* Bg = (const char*)Bt + (size_t)(n0 + srow) * 2048 + sswz;
  const u32 ldsb = (u32)(w * 1024);

#define GSTAGE3(buf, ks_)                                                         \
  do {                                                                            \
    u32 koff_ = (u32)(ks_) * 64;                                                  \
    GLD16(Ag + koff_, (char*)A_lds[buf] + ldsb);                                  \
    GLD16(Ag + koff_ + (size_t)64 * 2048, (char*)A_lds[buf] + 4096 + ldsb);       \
    GLD16(Bg + koff_, (char*)B_lds[buf] + ldsb);                                  \
  } while (0)

  f32x4 acc[2][4];
#pragma unroll
  for (int i = 0; i < 2; ++i)
#pragma unroll
    for (int j = 0; j < 4; ++j) acc[i][j] = (f32x4){0.f, 0.f, 0.f, 0.f};

  int cur = 0;
  GSTAGE3(0, 0);
  for (int ks = 0; ks < 32; ++ks) {
    GSTAGE3(cur ^ 1, (ks + 1) & 31);
    asm volatile("s_waitcnt vmcnt(3)" ::: "memory");
    __builtin_amdgcn_s_barrier();
    __builtin_amdgcn_sched_barrier(0);
    const char* Ac = (const char*)A_lds[cur];
    const char* Bc = (const char*)B_lds[cur];
    bf16x8 af[2], bfr[4];
#pragma unroll
    for (int i = 0; i < 2; ++i) {
      int row = w * 32 + i * 16 + c;
      af[i] = *(const bf16x8*)(Ac + row * 64 + ((g * 16) ^ ((row & 3) << 4)));
    }
#pragma unroll
    for (int j = 0; j < 4; ++j) {
      int row = j * 16 + c;
      bfr[j] = *(const bf16x8*)(Bc + row * 64 + ((g * 16) ^ ((row & 3) << 4)));
    }
    __builtin_amdgcn_s_setprio(1);
#pragma unroll
    for (int i = 0; i < 2; ++i)
#pragma unroll
      for (int j = 0; j < 4; ++j)
        acc[i][j] = __builtin_amdgcn_mfma_f32_16x16x32_bf16(af[i], bfr[j], acc[i][j], 0, 0, 0);
    __builtin_amdgcn_s_setprio(0);
    asm volatile("s_waitcnt lgkmcnt(0)" ::: "memory");
    __builtin_amdgcn_s_barrier();
    __builtin_amdgcn_sched_barrier(0);
    cur ^= 1;
  }
#undef GSTAGE3

#pragma unroll
  for (int i = 0; i < 2; ++i)
#pragma unroll
    for (int j = 0; j < 4; ++j)
#pragma unroll
      for (int r = 0; r < 4; ++r) {
        int m = m0 + w * 32 + i * 16 + g * 4 + r;
        int col = n0 + j * 16 + c;
        out[(size_t)m * 1024 + col] = acc[i][j][r] + bias[col];
      }
}

// ---------------- flash attention, swapped-QK^T 32x32, no-max exp2 softmax ----------------
// ROUND-6-EXACT structure (proven correct): double-buffered K/V, TWO barriers per
// KV tile (vmcnt(4)+barrier pre-compute; lgkmcnt(0)+barrier post-compute).
// 64 q-rows per wave (two 32-row groups). Early-softmax P-carry across the stagger.
template <int SPLIT>
__global__ __launch_bounds__(256, 2) void flash_attn_t(const u16* __restrict__ Qb,
                                                       const u16* __restrict__ Kb,
                                                       const u16* __restrict__ Vt,
                                                       u16* __restrict__ Ob,
                                                       float* __restrict__ Op,
                                                       float* __restrict__ Lp) {
  constexpr int NT = SPLIT ? 32 : 64;  // KV tiles per block
  __shared__ __align__(16) u16 K_lds[2][64 * 64];
  __shared__ __align__(16) u16 V_lds[2][64 * 64];
  const int tid = threadIdx.x;
  const int l = tid & 63, w = tid >> 6;
  const int lq = l & 31, hi = l >> 5;
  const int h = blockIdx.y;
  const int z = SPLIT ? blockIdx.z : 0;
  const int kb = z * 32;                      // KV tile base (split half)
  const int qb = blockIdx.x * 256 + w * 64;   // wave's 64-row q base
  const int q0 = qb + lq, q1 = qb + 32 + lq;

  bf16x8 qf0[4], qf1[4];
  {
    const u16* qr0 = Qb + (size_t)q0 * 1024 + h * 64;
    const u16* qr1 = Qb + (size_t)q1 * 1024 + h * 64;
#pragma unroll
    for (int dm = 0; dm < 4; ++dm) {
      qf0[dm] = *(const bf16x8*)(qr0 + dm * 16 + hi * 8);
      qf1[dm] = *(const bf16x8*)(qr1 + dm * 16 + hi * 8);
    }
  }

  f32x16 ot0[2], ot1[2];
#pragma unroll
  for (int a = 0; a < 2; ++a)
#pragma unroll
    for (int r = 0; r < 16; ++r) { ot0[a][r] = 0.f; ot1[a][r] = 0.f; }
  float lrow0 = 0.f, lrow1 = 0.f;
  u32 pkA0[16], pkA1[16], pkB0[16], pkB1[16];

  const int srow = tid >> 3;
  const u32 sswz = (u32)(((tid & 7) * 16) ^ ((srow & 7) << 4));
  const char* Kg = (const char*)Kb + ((size_t)srow * 1024 + h * 64) * 2 + sswz;
  const char* Vg = (const char*)Vt + ((size_t)(h * 64 + srow) * 4096) * 2 + sswz;
  const u32 ldsb = (u32)(w * 1024);

  // PV only: each V fragment read once, feeds both q-groups' accumulators
#define PVONLY(P0, P1, VSLOT)                                                     \
  {                                                                               \
    const char* Vp_ = (const char*)(VSLOT);                                       \
    __builtin_amdgcn_s_setprio(1);                                                \
    _Pragma("unroll") for (int sti_ = 0; sti_ < 4; ++sti_) {                      \
      u32x4 pw0_ = {P0[sti_ * 4 + 0], P0[sti_ * 4 + 1], P0[sti_ * 4 + 2],         \
                    P0[sti_ * 4 + 3]};                                            \
      u32x4 pw1_ = {P1[sti_ * 4 + 0], P1[sti_ * 4 + 1], P1[sti_ * 4 + 2],         \
                    P1[sti_ * 4 + 3]};                                            \
      bf16x8 pf0_ = __builtin_bit_cast(bf16x8, pw0_);                             \
      bf16x8 pf1_ = __builtin_bit_cast(bf16x8, pw1_);                             \
      const u32 cb_ = (u32)(sti_ * 32 + hi * 16);                                 \
      _Pragma("unroll") for (int a_ = 0; a_ < 2; ++a_) {                          \
        const int rowd_ = a_ * 32 + lq;                                           \
        const u32 rs_ = (u32)(rowd_ * 128), rz_ = (u32)((rowd_ & 7) << 4);        \
        bf16x8 vf_ = *(const bf16x8*)(Vp_ + rs_ + (cb_ ^ rz_));                   \
        ot0[a_] = __builtin_amdgcn_mfma_f32_32x32x16_bf16(vf_, pf0_, ot0[a_], 0, 0, 0); \
        ot1[a_] = __builtin_amdgcn_mfma_f32_32x32x16_bf16(vf_, pf1_, ot1[a_], 0, 0, 0); \
      }                                                                           \
    }                                                                             \
    __builtin_amdgcn_s_setprio(0);                                                \
  }

  // BODY: stage K(TI+1),V(TI); QK(TI) both groups (kf shared); PV(TI-1); softmax->pk
#define BODY(TI, C0, C1, P0, P1, DOPREV)                                          \
  {                                                                               \
    const int ti_ = (TI);                                                         \
    const int nxt_ = (ti_ + 1) & (NT - 1);                                        \
    {                                                                             \
      const char* kg_ = Kg + (size_t)(kb + nxt_) * 64 * 2048;                     \
      char* kl_ = (char*)K_lds[nxt_ & 1] + ldsb;                                  \
      GLD16(kg_, kl_);                                                            \
      GLD16(kg_ + 32 * 2048, kl_ + 4096);                                         \
      const char* vg_ = Vg + (size_t)(kb + ti_) * 128;                            \
      char* vl_ = (char*)V_lds[ti_ & 1] + ldsb;                                   \
      GLD16(vg_, vl_);                                                            \
      GLD16(vg_ + (size_t)32 * 8192, vl_ + 4096);                                 \
    }                                                                             \
    asm volatile("s_waitcnt vmcnt(4)" ::: "memory");                              \
    __builtin_amdgcn_s_barrier();                                                 \
    __builtin_amdgcn_sched_barrier(0);                                            \
    const char* Kc_ = (const char*)K_lds[ti_ & 1];                                \
    f32x16 st0_[2], st1_[2];                                                      \
    _Pragma("unroll") for (int s_ = 0; s_ < 2; ++s_)                              \
    _Pragma("unroll") for (int r_ = 0; r_ < 16; ++r_) {                           \
      st0_[s_][r_] = 0.f;                                                         \
      st1_[s_][r_] = 0.f;                                                         \
    }                                                                             \
    __builtin_amdgcn_s_setprio(1);                                                \
    _Pragma("unroll") for (int s_ = 0; s_ < 2; ++s_) {                            \
      const int row_ = s_ * 32 + lq;                                              \
      const u32 rs_ = (u32)(row_ * 128), rz_ = (u32)((row_ & 7) << 4);            \
      _Pragma("unroll") for (int dm_ = 0; dm_ < 4; ++dm_) {                       \
        bf16x8 kf_ = *(const bf16x8*)(Kc_ + rs_ + ((u32)(dm_ * 32 + hi * 16) ^ rz_)); \
        st0_[s_] = __builtin_amdgcn_mfma_f32_32x32x16_bf16(kf_, qf0[dm_], st0_[s_], 0, 0, 0); \
        st1_[s_] = __builtin_amdgcn_mfma_f32_32x32x16_bf16(kf_, qf1[dm_], st1_[s_], 0, 0, 0); \
      }                                                                           \
    }                                                                             \
    __builtin_amdgcn_s_setprio(0);                                                \
    if (DOPREV) PVONLY(P0, P1, V_lds[(ti_ - 1) & 1]);                             \
    float rs0_ = 0.f, rs1_ = 0.f;                                                 \
    _Pragma("unroll") for (int s_ = 0; s_ < 2; ++s_)                              \
    _Pragma("unroll") for (int j_ = 0; j_ < 8; ++j_) {                            \
      float a0_ = __builtin_amdgcn_exp2f(st0_[s_][2 * j_]);                       \
      float a1_ = __builtin_amdgcn_exp2f(st0_[s_][2 * j_ + 1]);                   \
      rs0_ += a0_ + a1_;                                                          \
      u32 wp0_;                                                                   \
      asm("v_cvt_pk_bf16_f32 %0, %1, %2" : "=v"(wp0_) : "v"(a0_), "v"(a1_));      \
      C0[s_ * 8 + j_] = wp0_;                                                     \
      float b0_ = __builtin_amdgcn_exp2f(st1_[s_][2 * j_]);                       \
      float b1_ = __builtin_amdgcn_exp2f(st1_[s_][2 * j_ + 1]);                   \
      rs1_ += b0_ + b1_;                                                          \
      u32 wp1_;                                                                   \
      asm("v_cvt_pk_bf16_f32 %0, %1, %2" : "=v"(wp1_) : "v"(b0_), "v"(b1_));      \
      C1[s_ * 8 + j_] = wp1_;                                                     \
    }                                                                             \
    lrow0 += rs0_;                                                                \
    lrow1 += rs1_;                                                                \
    asm volatile("s_waitcnt lgkmcnt(0)" ::: "memory");                            \
    __builtin_amdgcn_s_barrier();                                                 \
    __builtin_amdgcn_sched_barrier(0);                                            \
  }

  {  // prologue: stage K(kb)
    const char* kg0 = Kg + (size_t)kb * 64 * 2048;
    char* kl = (char*)K_lds[0] + ldsb;
    GLD16(kg0, kl);
    GLD16(kg0 + 32 * 2048, kl + 4096);
  }

  BODY(0, pkA0, pkA1, pkA0, pkA1, 0);
  for (int i = 1; i < NT - 1; i += 2) {
    BODY(i, pkB0, pkB1, pkA0, pkA1, 1);
    BODY(i + 1, pkA0, pkA1, pkB0, pkB1, 1);
  }
  BODY(NT - 1, pkB0, pkB1, pkA0, pkA1, 1);
  asm volatile("s_waitcnt vmcnt(0)" ::: "memory");
  __builtin_amdgcn_s_barrier();
  __builtin_amdgcn_sched_barrier(0);
  PVONLY(pkB0, pkB1, V_lds[(NT - 1) & 1]);

#undef BODY
#undef PVONLY

  lrow0 += __shfl_xor(lrow0, 32, 64);
  lrow1 += __shfl_xor(lrow1, 32, 64);
  if constexpr (SPLIT) {
    float* or0 = Op + (size_t)z * (4096 * 1024) + (size_t)q0 * 1024 + h * 64 + hi * 4;
    float* or1 = Op + (size_t)z * (4096 * 1024) + (size_t)q1 * 1024 + h * 64 + hi * 4;
#pragma unroll
    for (int a = 0; a < 2; ++a)
#pragma unroll
      for (int rr = 0; rr < 4; ++rr) {
        float4 f0 = {ot0[a][rr * 4 + 0], ot0[a][rr * 4 + 1], ot0[a][rr * 4 + 2],
                     ot0[a][rr * 4 + 3]};
        *(float4*)(or0 + a * 32 + rr * 8) = f0;
        float4 f1 = {ot1[a][rr * 4 + 0], ot1[a][rr * 4 + 1], ot1[a][rr * 4 + 2],
                     ot1[a][rr * 4 + 3]};
        *(float4*)(or1 + a * 32 + rr * 8) = f1;
      }
    if (hi == 0) {
      Lp[z * 65536 + h * 4096 + q0] = lrow0;
      Lp[z * 65536 + h * 4096 + q1] = lrow1;
    }
  } else {
    float inv0 = 1.f / lrow0, inv1 = 1.f / lrow1;
    u16* or0 = Ob + (size_t)q0 * 1024 + h * 64 + hi * 4;
    u16* or1 = Ob + (size_t)q1 * 1024 + h * 64 + hi * 4;
#pragma unroll
    for (int a = 0; a < 2; ++a)
#pragma unroll
      for (int rr = 0; rr < 4; ++rr) {
        ushort4 o4;
        o4.x = f2bf(ot0[a][rr * 4 + 0] * inv0);
        o4.y = f2bf(ot0[a][rr * 4 + 1] * inv0);
        o4.z = f2bf(ot0[a][rr * 4 + 2] * inv0);
        o4.w = f2bf(ot0[a][rr * 4 + 3] * inv0);
        *(ushort4*)(or0 + a * 32 + rr * 8) = o4;
        o4.x = f2bf(ot1[a][rr * 4 + 0] * inv1);
        o4.y = f2bf(ot1[a][rr * 4 + 1] * inv1);
        o4.z = f2bf(ot1[a][rr * 4 + 2] * inv1);
        o4.w = f2bf(ot1[a][rr * 4 + 3] * inv1);
        *(ushort4*)(or1 + a * 32 + rr * 8) = o4;
      }
  }
}

// ---------------- merge KV halves: Ob = (O0+O1)/(L0+L1), f32 -> bf16 ----------------
__global__ __launch_bounds__(256) void merge_halves(const float* __restrict__ O0,
                                                    const float* __restrict__ O1,
                                                    const float* __restrict__ L0,
                                                    const float* __restrict__ L1,
                                                    u16* __restrict__ Ob) {
  int idx = blockIdx.x * 256 + threadIdx.x;  // 8 cols each
  int q = idx >> 7;
  int c0 = (idx & 127) * 8;
  int h = c0 >> 6;
  float inv = 1.f / (L0[h * 4096 + q] + L1[h * 4096 + q]);
  size_t off = (size_t)q * 1024 + c0;
  float4 a0 = *(const float4*)(O0 + off), a1 = *(const float4*)(O0 + off + 4);
  float4 b0 = *(const float4*)(O1 + off), b1 = *(const float4*)(O1 + off + 4);
  ushort4 o0, o1;
  o0.x = f2bf((a0.x + b0.x) * inv);
  o0.y = f2bf((a0.y + b0.y) * inv);
  o0.z = f2bf((a0.z + b0.z) * inv);
  o0.w = f2bf((a0.w + b0.w) * inv);
  o1.x = f2bf((a1.x + b1.x) * inv);
  o1.y = f2bf((a1.y + b1.y) * inv);
  o1.z = f2bf((a1.z + b1.z) * inv);
  o1.w = f2bf((a1.w + b1.w) * inv);
  *(ushort4*)(Ob + off) = o0;
  *(ushort4*)(Ob + off + 4) = o1;
}

extern "C" void kernel_launch(void* const* d_in, const int* in_sizes, int n_in,
                              void* d_out, int out_size, void* d_ws, size_t ws_size,
                              hipStream_t stream) {
  const float* x = (const float*)d_in[0];
  const float* Wq = (const float*)d_in[1];
  const float* Wk = (const float*)d_in[2];
  const float* Wv = (const float*)d_in[3];
  const float* Wo = (const float*)d_in[4];
  const float* bo = (const float*)d_in[5];
  float* out = (float*)d_out;

  char* ws = (char*)d_ws;
  u16* xb  = (u16*)(ws);                  // 8 MB (dead after gemm_qkv; reused as ObM)
  u16* Wqt = (u16*)(ws + (8u << 20));     // 2 MB  [Wqt|Wkt|Wvt] contiguous
  u16* Wot = (u16*)(ws + (14u << 20));    // 2 MB
  u16* Qb  = (u16*)(ws + (16u << 20));    // 8 MB
  u16* Kbf = (u16*)(ws + (24u << 20));    // 8 MB
  u16* Vth = (u16*)(ws + (32u << 20));    // 8 MB  [h][64][n] (quad-interleaved n)
  u16* Ob  = (u16*)(ws + (40u << 20));    // 8 MB (fallback path output)
  float* Op = (float*)(ws + (40u << 20)); // 32 MB (split path: 2x f32 partials)
  float* Lp = (float*)(ws + (72u << 20)); // 512 KB (2x16x4096 f32)
  u16* Wkt = Wqt + (1u << 20);
  u16* Wvt = Wqt + (2u << 20);

  const bool split = ws_size >= ((73u << 20) + (1u << 19));

  cvt_bf16_kernel<<<2048, 256, 0, stream>>>(x, xb, 4096 * 1024);
  transpose4<<<dim3(16, 16, 4), 256, 0, stream>>>(Wq, Wk, Wv, Wo, Wqt, Wkt, Wvt, Wot);
  gemm_qkv<<<dim3(24, 32), 256, 0, stream>>>(xb, Wqt, Qb, Kbf, Vth);

  if (split) {
    flash_attn_t<1><<<dim3(16, 16, 2), 256, 0, stream>>>(Qb, Kbf, Vth, nullptr, Op, Lp);
    u16* ObM = (u16*)ws;  // reuse xb region
    merge_halves<<<2048, 256, 0, stream>>>(Op, Op + (1u << 22), Lp, Lp + 65536, ObM);
    gemm_out128<<<dim3(16, 32), 256, 0, stream>>>(ObM, Wot, out, bo);
  } else {
    flash_attn_t<0><<<dim3(16, 16, 1), 256, 0, stream>>>(Qb, Kbf, Vth, Ob, nullptr, nullptr);
    gemm_out128<<<dim3(16, 32), 256, 0, stream>>>(Ob, Wot, out, bo);
  }
}

// Round 11
// 174.341 us; speedup vs baseline: 1.0837x; 1.0837x over previous
//
#include <hip/hip_runtime.h>
#include <stdint.h>

#define NH 16
#define NN 4096

typedef __attribute__((ext_vector_type(8))) short bf16x8;
typedef __attribute__((ext_vector_type(4))) short bf16x4;
typedef __attribute__((ext_vector_type(4))) float f32x4;
typedef __attribute__((ext_vector_type(16))) float f32x16;
typedef unsigned short u16;
typedef unsigned int u32;
typedef __attribute__((ext_vector_type(4))) u32 u32x4;

__device__ __forceinline__ u16 f2bf(float f) {
  u32 u = __float_as_uint(f);
  return (u16)((u + 0x7FFFu + ((u >> 16) & 1u)) >> 16);
}

#define GLD16(gp, lp)                                              \
  __builtin_amdgcn_global_load_lds(                                \
      (__attribute__((address_space(1))) void*)(gp),               \
      (__attribute__((address_space(3))) void*)(lp), 16, 0, 0)

// ---------------- prep: fused weight transposes (z<4) + x f32->bf16 (z=4,5) ----------------
__global__ __launch_bounds__(256) void prep(const float* __restrict__ x,
                                            const float* __restrict__ Wq,
                                            const float* __restrict__ Wk,
                                            const float* __restrict__ Wv,
                                            const float* __restrict__ Wo,
                                            u16* __restrict__ xb,
                                            u16* __restrict__ Wqt, u16* __restrict__ Wkt,
                                            u16* __restrict__ Wvt, u16* __restrict__ Wot) {
  __shared__ float tile[64][65];
  int z = blockIdx.z;
  int tid = threadIdx.x;
  if (z >= 4) {
    // x convert: 512 blocks x 8192 floats
    int bi = (z - 4) * 256 + blockIdx.y * 16 + blockIdx.x;
    size_t base = (size_t)bi * 8192;
#pragma unroll
    for (int k = 0; k < 4; ++k) {
      size_t i = base + (size_t)k * 2048 + tid * 8;
      float4 a = *(const float4*)(x + i);
      float4 b = *(const float4*)(x + i + 4);
      uint4 o;
      o.x = (u32)f2bf(a.x) | ((u32)f2bf(a.y) << 16);
      o.y = (u32)f2bf(a.z) | ((u32)f2bf(a.w) << 16);
      o.z = (u32)f2bf(b.x) | ((u32)f2bf(b.y) << 16);
      o.w = (u32)f2bf(b.z) | ((u32)f2bf(b.w) << 16);
      *(uint4*)(xb + i) = o;
    }
    return;
  }
  const float* src;
  u16* dst;
  float scale = 1.0f;
  if (z == 0) { src = Wq; dst = Wqt; scale = 0.125f * 1.4426950408889634f; }
  else if (z == 1) { src = Wk; dst = Wkt; }
  else if (z == 2) { src = Wv; dst = Wvt; }
  else { src = Wo; dst = Wot; }
  int tx = tid & 63, ty = tid >> 6;
  int c0 = blockIdx.x * 64, r0 = blockIdx.y * 64;
#pragma unroll
  for (int i = ty; i < 64; i += 4)
    tile[i][tx] = src[(size_t)(r0 + i) * 1024 + c0 + tx];
  __syncthreads();
#pragma unroll
  for (int i = ty; i < 64; i += 4)
    dst[(size_t)(c0 + i) * 1024 + r0 + tx] = f2bf(tile[tx][i] * scale);
}

// ---------------- fused QKV GEMM: [4096][1024] @ Wt[3072][1024]^T ----------------
// V (sec==2): acc -> swizzled LDS tile (reusing staging LDS) -> coalesced V^T stores
// with n-within-16 quads interleaved [0,2,1,3] (so flash PV reads are single b128).
__global__ __launch_bounds__(256) void gemm_qkv(const u16* __restrict__ A,
                                                const u16* __restrict__ Bt,
                                                u16* __restrict__ Qb, u16* __restrict__ Kb,
                                                u16* __restrict__ Vth) {
  __shared__ __align__(16) u16 SH[16384];  // 32KB: A buffers [0,8192), B buffers [8192,16384)
  u16* A_lds = SH;
  u16* B_lds = SH + 8192;
  const int tid = threadIdx.x;
  const int l = tid & 63, w = tid >> 6;
  const int g = l >> 4, c = l & 15;
  const int wr = w >> 1, wc = w & 1;
  const int m0 = blockIdx.y * 128, n0 = blockIdx.x * 128;

  const int srow = tid >> 2;
  const u32 sswz = (u32)(((tid & 3) * 16) ^ ((srow & 3) << 4));
  const char* Ag = (const char*)A + (size_t)(m0 + srow) * 2048 + sswz;
  const char* Bg = (const char*)Bt + (size_t)(n0 + srow) * 2048 + sswz;
  const u32 ldsb = (u32)(w * 1024);

#define GSTAGE(buf, ks_)                                                          \
  do {                                                                            \
    u32 koff_ = (u32)(ks_) * 64;                                                  \
    _Pragma("unroll") for (int p_ = 0; p_ < 2; ++p_) {                            \
      GLD16(Ag + koff_ + (size_t)p_ * 64 * 2048,                                  \
            (char*)A_lds + (buf) * 8192 + p_ * 4096 + ldsb);                      \
      GLD16(Bg + koff_ + (size_t)p_ * 64 * 2048,                                  \
            (char*)B_lds + (buf) * 8192 + p_ * 4096 + ldsb);                      \
    }                                                                             \
  } while (0)

  f32x4 acc[4][4];
#pragma unroll
  for (int i = 0; i < 4; ++i)
#pragma unroll
    for (int j = 0; j < 4; ++j) acc[i][j] = (f32x4){0.f, 0.f, 0.f, 0.f};

  int cur = 0;
  GSTAGE(0, 0);
  for (int ks = 0; ks < 32; ++ks) {
    GSTAGE(cur ^ 1, (ks + 1) & 31);
    asm volatile("s_waitcnt vmcnt(4)" ::: "memory");
    __builtin_amdgcn_s_barrier();
    __builtin_amdgcn_sched_barrier(0);
    const char* Ac = (const char*)A_lds + cur * 8192;
    const char* Bc = (const char*)B_lds + cur * 8192;
    bf16x8 af[4], bfr[4];
#pragma unroll
    for (int i = 0; i < 4; ++i) {
      int row = wr * 64 + i * 16 + c;
      af[i] = *(const bf16x8*)(Ac + row * 64 + ((g * 16) ^ ((row & 3) << 4)));
    }
#pragma unroll
    for (int j = 0; j < 4; ++j) {
      int row = wc * 64 + j * 16 + c;
      bfr[j] = *(const bf16x8*)(Bc + row * 64 + ((g * 16) ^ ((row & 3) << 4)));
    }
    __builtin_amdgcn_s_setprio(1);
#pragma unroll
    for (int i = 0; i < 4; ++i)
#pragma unroll
      for (int j = 0; j < 4; ++j)
        acc[i][j] = __builtin_amdgcn_mfma_f32_16x16x32_bf16(af[i], bfr[j], acc[i][j], 0, 0, 0);
    __builtin_amdgcn_s_setprio(0);
    asm volatile("s_waitcnt lgkmcnt(0)" ::: "memory");
    __builtin_amdgcn_s_barrier();
    __builtin_amdgcn_sched_barrier(0);
    cur ^= 1;
  }
#undef GSTAGE

  const int sec = n0 >> 10;  // block-uniform: 0=Q, 1=K, 2=V
  if (sec < 2) {
#pragma unroll
    for (int i = 0; i < 4; ++i)
#pragma unroll
      for (int j = 0; j < 4; ++j)
#pragma unroll
        for (int r = 0; r < 4; ++r) {
          int m = m0 + wr * 64 + i * 16 + g * 4 + r;
          int cc = (n0 + wc * 64 + j * 16 + c) & 1023;
          u16 v = f2bf(acc[i][j][r]);
          if (sec == 0) Qb[(size_t)m * 1024 + cc] = v;
          else Kb[(size_t)m * 1024 + cc] = v;
        }
  } else {
    // V^T via LDS transpose (loop's final barrier already synced; SH is free).
    const int gq = ((g & 1) << 1) | (g >> 1);  // quad-swap 1<->2 for V n-order
    const int cc0 = n0 & 1023;
#pragma unroll
    for (int i = 0; i < 4; ++i)
#pragma unroll
      for (int j = 0; j < 4; ++j)
#pragma unroll
        for (int r = 0; r < 4; ++r) {
          int cl = wc * 64 + j * 16 + c;            // local col (d)
          int mql = wr * 64 + i * 16 + gq * 4 + r;  // local n, quad-interleaved
          SH[cl * 128 + (mql ^ ((cl & 15) << 3))] = f2bf(acc[i][j][r]);
        }
    __syncthreads();
#pragma unroll
    for (int p = 0; p < 4; ++p) {
      int row = p * 32 + (tid >> 3);
#pragma unroll
      for (int half = 0; half < 2; ++half) {
        int mq = (tid & 7) * 8 + half * 64;
        bf16x8 vv = *(const bf16x8*)&SH[row * 128 + (mq ^ ((row & 15) << 3))];
        *(bf16x8*)(Vth + (size_t)(cc0 + row) * 4096 + m0 + mq) = vv;
      }
    }
  }
}

// ---------------- out-proj GEMM, 128x64 tiles: out[4096][1024] = A @ Wot^T + bo ----------------
__global__ __launch_bounds__(256) void gemm_out128(const u16* __restrict__ A,
                                                   const u16* __restrict__ Bt,
                                                   float* __restrict__ out,
                                                   const float* __restrict__ bias) {
  __shared__ __align__(16) u16 A_lds[2][128 * 32];
  __shared__ __align__(16) u16 B_lds[2][64 * 32];
  const int tid = threadIdx.x;
  const int l = tid & 63, w = tid >> 6;
  const int g = l >> 4, c = l & 15;
  const int m0 = blockIdx.y * 128, n0 = blockIdx.x * 64;

  const int srow = tid >> 2;
  const u32 sswz = (u32)(((tid & 3) * 16) ^ ((srow & 3) << 4));
  const char* Ag = (const char*)A + (size_t)(m0 + srow) * 2048 + sswz;
  const char* Bg = (const char*)Bt + (size_t)(n0 + srow) * 2048 + sswz;
  const u32 ldsb = (u32)(w * 1024);

#define GSTAGE3(buf, ks_)                                                         \
  do {                                                                            \
    u32 koff_ = (u32)(ks_) * 64;                                                  \
    GLD16(Ag + koff_, (char*)A_lds[buf] + ldsb);                                  \
    GLD16(Ag + koff_ + (size_t)64 * 2048, (char*)A_lds[buf] + 4096 + ldsb);       \
    GLD16(Bg + koff_, (char*)B_lds[buf] + ldsb);                                  \
  } while (0)

  f32x4 acc[2][4];
#pragma unroll
  for (int i = 0; i < 2; ++i)
#pragma unroll
    for (int j = 0; j < 4; ++j) acc[i][j] = (f32x4){0.f, 0.f, 0.f, 0.f};

  int cur = 0;
  GSTAGE3(0, 0);
  for (int ks = 0; ks < 32; ++ks) {
    GSTAGE3(cur ^ 1, (ks + 1) & 31);
    asm volatile("s_waitcnt vmcnt(3)" ::: "memory");
    __builtin_amdgcn_s_barrier();
    __builtin_amdgcn_sched_barrier(0);
    const char* Ac = (const char*)A_lds[cur];
    const char* Bc = (const char*)B_lds[cur];
    bf16x8 af[2], bfr[4];
#pragma unroll
    for (int i = 0; i < 2; ++i) {
      int row = w * 32 + i * 16 + c;
      af[i] = *(const bf16x8*)(Ac + row * 64 + ((g * 16) ^ ((row & 3) << 4)));
    }
#pragma unroll
    for (int j = 0; j < 4; ++j) {
      int row = j * 16 + c;
      bfr[j] = *(const bf16x8*)(Bc + row * 64 + ((g * 16) ^ ((row & 3) << 4)));
    }
    __builtin_amdgcn_s_setprio(1);
#pragma unroll
    for (int i = 0; i < 2; ++i)
#pragma unroll
      for (int j = 0; j < 4; ++j)
        acc[i][j] = __builtin_amdgcn_mfma_f32_16x16x32_bf16(af[i], bfr[j], acc[i][j], 0, 0, 0);
    __builtin_amdgcn_s_setprio(0);
    asm volatile("s_waitcnt lgkmcnt(0)" ::: "memory");
    __builtin_amdgcn_s_barrier();
    __builtin_amdgcn_sched_barrier(0);
    cur ^= 1;
  }
#undef GSTAGE3

#pragma unroll
  for (int i = 0; i < 2; ++i)
#pragma unroll
    for (int j = 0; j < 4; ++j)
#pragma unroll
      for (int r = 0; r < 4; ++r) {
        int m = m0 + w * 32 + i * 16 + g * 4 + r;
        int col = n0 + j * 16 + c;
        out[(size_t)m * 1024 + col] = acc[i][j][r] + bias[col];
      }
}

// ---------------- flash attention: 128-wide bodies, proven 2-barrier skeleton ----------------
// Each body handles TWO 64-KV tiles between ONE barrier pair (vmcnt(8)+barrier pre,
// lgkmcnt(0)+barrier post — identical semantics to the proven round-6 skeleton).
// 4-slot LDS ring (t -> slot t%4), statically unrolled even/odd bodies.
// Body b: stage K(2b+2),K(2b+3),V(2b+1),V(2b+2); QK(2b)->sm->pkX; PV(2b-1)[pkP];
// QK(2b+1); PV(2b)[pkX]; sm->pkP.  All WAR pairs are protected by the end barrier.
template <int SPLIT>
__global__ __launch_bounds__(256, 2) void flash_attn_t(const u16* __restrict__ Qb,
                                                       const u16* __restrict__ Kb,
                                                       const u16* __restrict__ Vt,
                                                       u16* __restrict__ Ob,
                                                       float* __restrict__ Op,
                                                       float* __restrict__ Lp) {
  constexpr int NT = SPLIT ? 32 : 64;  // KV tiles per block
  constexpr int NB = NT / 2;           // bodies
  __shared__ __align__(16) u16 K_lds[4][64 * 64];
  __shared__ __align__(16) u16 V_lds[4][64 * 64];
  const int tid = threadIdx.x;
  const int l = tid & 63, w = tid >> 6;
  const int lq = l & 31, hi = l >> 5;
  const int h = blockIdx.y;
  const int z = SPLIT ? blockIdx.z : 0;
  const int kb = z * 32;                      // KV tile base (split half)
  const int qb = blockIdx.x * 256 + w * 64;   // wave's 64-row q base
  const int q0 = qb + lq, q1 = qb + 32 + lq;

  bf16x8 qf0[4], qf1[4];
  {
    const u16* qr0 = Qb + (size_t)q0 * 1024 + h * 64;
    const u16* qr1 = Qb + (size_t)q1 * 1024 + h * 64;
#pragma unroll
    for (int dm = 0; dm < 4; ++dm) {
      qf0[dm] = *(const bf16x8*)(qr0 + dm * 16 + hi * 8);
      qf1[dm] = *(const bf16x8*)(qr1 + dm * 16 + hi * 8);
    }
  }

  f32x16 ot0[2], ot1[2];
#pragma unroll
  for (int a = 0; a < 2; ++a)
#pragma unroll
    for (int r = 0; r < 16; ++r) { ot0[a][r] = 0.f; ot1[a][r] = 0.f; }
  float lrow0 = 0.f, lrow1 = 0.f;
  u32 pkP0[16], pkP1[16], pkX0[16], pkX1[16];

  const int srow = tid >> 3;
  const u32 sswz = (u32)(((tid & 7) * 16) ^ ((srow & 7) << 4));
  const char* Kg = (const char*)Kb + ((size_t)srow * 1024 + h * 64) * 2 + sswz;
  const char* Vg = (const char*)Vt + ((size_t)(h * 64 + srow) * 4096) * 2 + sswz;
  const u32 ldsb = (u32)(w * 1024);

#define STAGE_K(T, SLOT)                                                          \
  {                                                                               \
    const char* kg_ = Kg + (size_t)(kb + ((T) & (NT - 1))) * 64 * 2048;           \
    char* kl_ = (char*)K_lds[SLOT] + ldsb;                                        \
    GLD16(kg_, kl_);                                                              \
    GLD16(kg_ + 32 * 2048, kl_ + 4096);                                           \
  }
#define STAGE_V(T, SLOT)                                                          \
  {                                                                               \
    const char* vg_ = Vg + (size_t)(kb + ((T) & (NT - 1))) * 128;                 \
    char* vl_ = (char*)V_lds[SLOT] + ldsb;                                        \
    GLD16(vg_, vl_);                                                              \
    GLD16(vg_ + (size_t)32 * 8192, vl_ + 4096);                                   \
  }

  // QK both q-groups from K slot -> st0_/st1_
#define QK2(SLOT, ST0, ST1)                                                       \
  {                                                                               \
    const char* Kc_ = (const char*)K_lds[SLOT];                                   \
    _Pragma("unroll") for (int s_ = 0; s_ < 2; ++s_)                              \
    _Pragma("unroll") for (int r_ = 0; r_ < 16; ++r_) {                           \
      ST0[s_][r_] = 0.f;                                                          \
      ST1[s_][r_] = 0.f;                                                          \
    }                                                                             \
    __builtin_amdgcn_s_setprio(1);                                                \
    _Pragma("unroll") for (int s_ = 0; s_ < 2; ++s_) {                            \
      const int row_ = s_ * 32 + lq;                                              \
      const u32 rs_ = (u32)(row_ * 128), rz_ = (u32)((row_ & 7) << 4);            \
      _Pragma("unroll") for (int dm_ = 0; dm_ < 4; ++dm_) {                       \
        bf16x8 kf_ = *(const bf16x8*)(Kc_ + rs_ + ((u32)(dm_ * 32 + hi * 16) ^ rz_)); \
        ST0[s_] = __builtin_amdgcn_mfma_f32_32x32x16_bf16(kf_, qf0[dm_], ST0[s_], 0, 0, 0); \
        ST1[s_] = __builtin_amdgcn_mfma_f32_32x32x16_bf16(kf_, qf1[dm_], ST1[s_], 0, 0, 0); \
      }                                                                           \
    }                                                                             \
    __builtin_amdgcn_s_setprio(0);                                                \
  }

  // softmax (no-max exp2) -> packed bf16
#define SM2(ST0, ST1, D0, D1)                                                     \
  {                                                                               \
    float rs0_ = 0.f, rs1_ = 0.f;                                                 \
    _Pragma("unroll") for (int s_ = 0; s_ < 2; ++s_)                              \
    _Pragma("unroll") for (int j_ = 0; j_ < 8; ++j_) {                            \
      float a0_ = __builtin_amdgcn_exp2f(ST0[s_][2 * j_]);                        \
      float a1_ = __builtin_amdgcn_exp2f(ST0[s_][2 * j_ + 1]);                    \
      rs0_ += a0_ + a1_;                                                          \
      u32 wp0_;                                                                   \
      asm("v_cvt_pk_bf16_f32 %0, %1, %2" : "=v"(wp0_) : "v"(a0_), "v"(a1_));      \
      D0[s_ * 8 + j_] = wp0_;                                                     \
      float b0_ = __builtin_amdgcn_exp2f(ST1[s_][2 * j_]);                        \
      float b1_ = __builtin_amdgcn_exp2f(ST1[s_][2 * j_ + 1]);                    \
      rs1_ += b0_ + b1_;                                                          \
      u32 wp1_;                                                                   \
      asm("v_cvt_pk_bf16_f32 %0, %1, %2" : "=v"(wp1_) : "v"(b0_), "v"(b1_));      \
      D1[s_ * 8 + j_] = wp1_;                                                     \
    }                                                                             \
    lrow0 += rs0_;                                                                \
    lrow1 += rs1_;                                                                \
  }

#define PV2(P0, P1, SLOT)                                                         \
  {                                                                               \
    const char* Vp_ = (const char*)V_lds[SLOT];                                   \
    __builtin_amdgcn_s_setprio(1);                                                \
    _Pragma("unroll") for (int sti_ = 0; sti_ < 4; ++sti_) {                      \
      u32x4 pw0_ = {P0[sti_ * 4 + 0], P0[sti_ * 4 + 1], P0[sti_ * 4 + 2],         \
                    P0[sti_ * 4 + 3]};                                            \
      u32x4 pw1_ = {P1[sti_ * 4 + 0], P1[sti_ * 4 + 1], P1[sti_ * 4 + 2],         \
                    P1[sti_ * 4 + 3]};                                            \
      bf16x8 pf0_ = __builtin_bit_cast(bf16x8, pw0_);                             \
      bf16x8 pf1_ = __builtin_bit_cast(bf16x8, pw1_);                             \
      const u32 cb_ = (u32)(sti_ * 32 + hi * 16);                                 \
      _Pragma("unroll") for (int a_ = 0; a_ < 2; ++a_) {                          \
        const int rowd_ = a_ * 32 + lq;                                           \
        const u32 rs_ = (u32)(rowd_ * 128), rz_ = (u32)((rowd_ & 7) << 4);        \
        bf16x8 vf_ = *(const bf16x8*)(Vp_ + rs_ + (cb_ ^ rz_));                   \
        ot0[a_] = __builtin_amdgcn_mfma_f32_32x32x16_bf16(vf_, pf0_, ot0[a_], 0, 0, 0); \
        ot1[a_] = __builtin_amdgcn_mfma_f32_32x32x16_bf16(vf_, pf1_, ot1[a_], 0, 0, 0); \
      }                                                                           \
    }                                                                             \
    __builtin_amdgcn_s_setprio(0);                                                \
  }

  // BODY2(T0, SK0r,SK1r, SKs0,SKs1, SVp,SV0r, SVs0,SVs1, DOPREV)
#define BODY2(T0, SK0r, SK1r, SKs0, SKs1, SVp, SV0r, SVs0, SVs1, DOPREV)          \
  {                                                                               \
    STAGE_K((T0) + 2, SKs0);                                                      \
    STAGE_K((T0) + 3, SKs1);                                                      \
    STAGE_V((T0) + 1, SVs0);                                                      \
    STAGE_V((T0) + 2, SVs1);                                                      \
    asm volatile("s_waitcnt vmcnt(8)" ::: "memory");                              \
    __builtin_amdgcn_s_barrier();                                                 \
    __builtin_amdgcn_sched_barrier(0);                                            \
    f32x16 st0_[2], st1_[2];                                                      \
    QK2(SK0r, st0_, st1_);                                                        \
    SM2(st0_, st1_, pkX0, pkX1);                                                  \
    if (DOPREV) PV2(pkP0, pkP1, SVp);                                             \
    QK2(SK1r, st0_, st1_);                                                        \
    PV2(pkX0, pkX1, SV0r);                                                        \
    SM2(st0_, st1_, pkP0, pkP1);                                                  \
    asm volatile("s_waitcnt lgkmcnt(0)" ::: "memory");                            \
    __builtin_amdgcn_s_barrier();                                                 \
    __builtin_amdgcn_sched_barrier(0);                                            \
  }

  // prologue: K(0)->0, K(1)->1, V(0)->0
  STAGE_K(0, 0);
  STAGE_K(1, 1);
  STAGE_V(0, 0);

  // body 0 (even), then pairs (odd, even), then final body NB-1 (odd)
  BODY2(0, 0, 1, 2, 3, 3, 0, 1, 2, 0);
  for (int b = 1; b + 1 < NB; b += 2) {
    BODY2(2 * b, 2, 3, 0, 1, 1, 2, 3, 0, 1);        // odd body
    BODY2(2 * (b + 1), 0, 1, 2, 3, 3, 0, 1, 2, 1);  // even body
  }
  BODY2(2 * (NB - 1), 2, 3, 0, 1, 1, 2, 3, 0, 1);   // final odd body
  // epilogue: all own loads landed + all waves' V(NT-1) (slot 3) visible
  asm volatile("s_waitcnt vmcnt(0) lgkmcnt(0)" ::: "memory");
  __builtin_amdgcn_s_barrier();
  __builtin_amdgcn_sched_barrier(0);
  PV2(pkP0, pkP1, 3);

#undef BODY2
#undef PV2
#undef SM2
#undef QK2
#undef STAGE_K
#undef STAGE_V

  lrow0 += __shfl_xor(lrow0, 32, 64);
  lrow1 += __shfl_xor(lrow1, 32, 64);
  if constexpr (SPLIT) {
    float* or0 = Op + (size_t)z * (4096 * 1024) + (size_t)q0 * 1024 + h * 64 + hi * 4;
    float* or1 = Op + (size_t)z * (4096 * 1024) + (size_t)q1 * 1024 + h * 64 + hi * 4;
#pragma unroll
    for (int a = 0; a < 2; ++a)
#pragma unroll
      for (int rr = 0; rr < 4; ++rr) {
        float4 f0 = {ot0[a][rr * 4 + 0], ot0[a][rr * 4 + 1], ot0[a][rr * 4 + 2],
                     ot0[a][rr * 4 + 3]};
        *(float4*)(or0 + a * 32 + rr * 8) = f0;
        float4 f1 = {ot1[a][rr * 4 + 0], ot1[a][rr * 4 + 1], ot1[a][rr * 4 + 2],
                     ot1[a][rr * 4 + 3]};
        *(float4*)(or1 + a * 32 + rr * 8) = f1;
      }
    if (hi == 0) {
      Lp[z * 65536 + h * 4096 + q0] = lrow0;
      Lp[z * 65536 + h * 4096 + q1] = lrow1;
    }
  } else {
    float inv0 = 1.f / lrow0, inv1 = 1.f / lrow1;
    u16* or0 = Ob + (size_t)q0 * 1024 + h * 64 + hi * 4;
    u16* or1 = Ob + (size_t)q1 * 1024 + h * 64 + hi * 4;
#pragma unroll
    for (int a = 0; a < 2; ++a)
#pragma unroll
      for (int rr = 0; rr < 4; ++rr) {
        ushort4 o4;
        o4.x = f2bf(ot0[a][rr * 4 + 0] * inv0);
        o4.y = f2bf(ot0[a][rr * 4 + 1] * inv0);
        o4.z = f2bf(ot0[a][rr * 4 + 2] * inv0);
        o4.w = f2bf(ot0[a][rr * 4 + 3] * inv0);
        *(ushort4*)(or0 + a * 32 + rr * 8) = o4;
        o4.x = f2bf(ot1[a][rr * 4 + 0] * inv1);
        o4.y = f2bf(ot1[a][rr * 4 + 1] * inv1);
        o4.z = f2bf(ot1[a][rr * 4 + 2] * inv1);
        o4.w = f2bf(ot1[a][rr * 4 + 3] * inv1);
        *(ushort4*)(or1 + a * 32 + rr * 8) = o4;
      }
  }
}

// ---------------- merge KV halves: Ob = (O0+O1)/(L0+L1), f32 -> bf16 ----------------
__global__ __launch_bounds__(256) void merge_halves(const float* __restrict__ O0,
                                                    const float* __restrict__ O1,
                                                    const float* __restrict__ L0,
                                                    const float* __restrict__ L1,
                                                    u16* __restrict__ Ob) {
  int idx = blockIdx.x * 256 + threadIdx.x;  // 8 cols each
  int q = idx >> 7;
  int c0 = (idx & 127) * 8;
  int h = c0 >> 6;
  float inv = 1.f / (L0[h * 4096 + q] + L1[h * 4096 + q]);
  size_t off = (size_t)q * 1024 + c0;
  float4 a0 = *(const float4*)(O0 + off), a1 = *(const float4*)(O0 + off + 4);
  float4 b0 = *(const float4*)(O1 + off), b1 = *(const float4*)(O1 + off + 4);
  ushort4 o0, o1;
  o0.x = f2bf((a0.x + b0.x) * inv);
  o0.y = f2bf((a0.y + b0.y) * inv);
  o0.z = f2bf((a0.z + b0.z) * inv);
  o0.w = f2bf((a0.w + b0.w) * inv);
  o1.x = f2bf((a1.x + b1.x) * inv);
  o1.y = f2bf((a1.y + b1.y) * inv);
  o1.z = f2bf((a1.z + b1.z) * inv);
  o1.w = f2bf((a1.w + b1.w) * inv);
  *(ushort4*)(Ob + off) = o0;
  *(ushort4*)(Ob + off + 4) = o1;
}

extern "C" void kernel_launch(void* const* d_in, const int* in_sizes, int n_in,
                              void* d_out, int out_size, void* d_ws, size_t ws_size,
                              hipStream_t stream) {
  const float* x = (const float*)d_in[0];
  const float* Wq = (const float*)d_in[1];
  const float* Wk = (const float*)d_in[2];
  const float* Wv = (const float*)d_in[3];
  const float* Wo = (const float*)d_in[4];
  const float* bo = (const float*)d_in[5];
  float* out = (float*)d_out;

  char* ws = (char*)d_ws;
  u16* xb  = (u16*)(ws);                  // 8 MB (dead after gemm_qkv; reused as ObM)
  u16* Wqt = (u16*)(ws + (8u << 20));     // 2 MB  [Wqt|Wkt|Wvt] contiguous
  u16* Wot = (u16*)(ws + (14u << 20));    // 2 MB
  u16* Qb  = (u16*)(ws + (16u << 20));    // 8 MB
  u16* Kbf = (u16*)(ws + (24u << 20));    // 8 MB
  u16* Vth = (u16*)(ws + (32u << 20));    // 8 MB  [h][64][n] (quad-interleaved n)
  u16* Ob  = (u16*)(ws + (40u << 20));    // 8 MB (fallback path output)
  float* Op = (float*)(ws + (40u << 20)); // 32 MB (split path: 2x f32 partials)
  float* Lp = (float*)(ws + (72u << 20)); // 512 KB (2x16x4096 f32)
  u16* Wkt = Wqt + (1u << 20);
  u16* Wvt = Wqt + (2u << 20);

  const bool split = ws_size >= ((73u << 20) + (1u << 19));

  prep<<<dim3(16, 16, 6), 256, 0, stream>>>(x, Wq, Wk, Wv, Wo, xb, Wqt, Wkt, Wvt, Wot);
  gemm_qkv<<<dim3(24, 32), 256, 0, stream>>>(xb, Wqt, Qb, Kbf, Vth);

  if (split) {
    flash_attn_t<1><<<dim3(16, 16, 2), 256, 0, stream>>>(Qb, Kbf, Vth, nullptr, Op, Lp);
    u16* ObM = (u16*)ws;  // reuse xb region
    merge_halves<<<2048, 256, 0, stream>>>(Op, Op + (1u << 22), Lp, Lp + 65536, ObM);
    gemm_out128<<<dim3(16, 32), 256, 0, stream>>>(ObM, Wot, out, bo);
  } else {
    flash_attn_t<0><<<dim3(16, 16, 1), 256, 0, stream>>>(Qb, Kbf, Vth, Ob, nullptr, nullptr);
    gemm_out128<<<dim3(16, 32), 256, 0, stream>>>(Ob, Wot, out, bo);
  }
}

// Round 12
// 162.398 us; speedup vs baseline: 1.1634x; 1.0735x over previous
//
#include <hip/hip_runtime.h>
#include <stdint.h>

#define NH 16
#define NN 4096

typedef __attribute__((ext_vector_type(8))) short bf16x8;
typedef __attribute__((ext_vector_type(4))) short bf16x4;
typedef __attribute__((ext_vector_type(4))) float f32x4;
typedef __attribute__((ext_vector_type(16))) float f32x16;
typedef unsigned short u16;
typedef unsigned int u32;
typedef __attribute__((ext_vector_type(4))) u32 u32x4;

__device__ __forceinline__ u16 f2bf(float f) {
  u32 u = __float_as_uint(f);
  return (u16)((u + 0x7FFFu + ((u >> 16) & 1u)) >> 16);
}

#define GLD16(gp, lp)                                              \
  __builtin_amdgcn_global_load_lds(                                \
      (__attribute__((address_space(1))) void*)(gp),               \
      (__attribute__((address_space(3))) void*)(lp), 16, 0, 0)

// ---------------- prep: fused weight transposes (z<4) + x f32->bf16 (z=4,5) ----------------
__global__ __launch_bounds__(256) void prep(const float* __restrict__ x,
                                            const float* __restrict__ Wq,
                                            const float* __restrict__ Wk,
                                            const float* __restrict__ Wv,
                                            const float* __restrict__ Wo,
                                            u16* __restrict__ xb,
                                            u16* __restrict__ Wqt, u16* __restrict__ Wkt,
                                            u16* __restrict__ Wvt, u16* __restrict__ Wot) {
  __shared__ float tile[64][65];
  int z = blockIdx.z;
  int tid = threadIdx.x;
  if (z >= 4) {
    int bi = (z - 4) * 256 + blockIdx.y * 16 + blockIdx.x;
    size_t base = (size_t)bi * 8192;
#pragma unroll
    for (int k = 0; k < 4; ++k) {
      size_t i = base + (size_t)k * 2048 + tid * 8;
      float4 a = *(const float4*)(x + i);
      float4 b = *(const float4*)(x + i + 4);
      uint4 o;
      o.x = (u32)f2bf(a.x) | ((u32)f2bf(a.y) << 16);
      o.y = (u32)f2bf(a.z) | ((u32)f2bf(a.w) << 16);
      o.z = (u32)f2bf(b.x) | ((u32)f2bf(b.y) << 16);
      o.w = (u32)f2bf(b.z) | ((u32)f2bf(b.w) << 16);
      *(uint4*)(xb + i) = o;
    }
    return;
  }
  const float* src;
  u16* dst;
  float scale = 1.0f;
  if (z == 0) { src = Wq; dst = Wqt; scale = 0.125f * 1.4426950408889634f; }
  else if (z == 1) { src = Wk; dst = Wkt; }
  else if (z == 2) { src = Wv; dst = Wvt; }
  else { src = Wo; dst = Wot; }
  int tx = tid & 63, ty = tid >> 6;
  int c0 = blockIdx.x * 64, r0 = blockIdx.y * 64;
#pragma unroll
  for (int i = ty; i < 64; i += 4)
    tile[i][tx] = src[(size_t)(r0 + i) * 1024 + c0 + tx];
  __syncthreads();
#pragma unroll
  for (int i = ty; i < 64; i += 4)
    dst[(size_t)(c0 + i) * 1024 + r0 + tx] = f2bf(tile[tx][i] * scale);
}

// ---------------- fused QKV GEMM: [4096][1024] @ Wt[3072][1024]^T ----------------
// V (sec==2): acc -> swizzled LDS tile (reusing staging LDS) -> coalesced V^T stores
// with n-within-16 quads interleaved [0,2,1,3] (so flash PV reads are single b128).
__global__ __launch_bounds__(256) void gemm_qkv(const u16* __restrict__ A,
                                                const u16* __restrict__ Bt,
                                                u16* __restrict__ Qb, u16* __restrict__ Kb,
                                                u16* __restrict__ Vth) {
  __shared__ __align__(16) u16 SH[16384];  // 32KB
  u16* A_lds = SH;
  u16* B_lds = SH + 8192;
  const int tid = threadIdx.x;
  const int l = tid & 63, w = tid >> 6;
  const int g = l >> 4, c = l & 15;
  const int wr = w >> 1, wc = w & 1;
  const int m0 = blockIdx.y * 128, n0 = blockIdx.x * 128;

  const int srow = tid >> 2;
  const u32 sswz = (u32)(((tid & 3) * 16) ^ ((srow & 3) << 4));
  const char* Ag = (const char*)A + (size_t)(m0 + srow) * 2048 + sswz;
  const char* Bg = (const char*)Bt + (size_t)(n0 + srow) * 2048 + sswz;
  const u32 ldsb = (u32)(w * 1024);

#define GSTAGE(buf, ks_)                                                          \
  do {                                                                            \
    u32 koff_ = (u32)(ks_) * 64;                                                  \
    _Pragma("unroll") for (int p_ = 0; p_ < 2; ++p_) {                            \
      GLD16(Ag + koff_ + (size_t)p_ * 64 * 2048,                                  \
            (char*)A_lds + (buf) * 8192 + p_ * 4096 + ldsb);                      \
      GLD16(Bg + koff_ + (size_t)p_ * 64 * 2048,                                  \
            (char*)B_lds + (buf) * 8192 + p_ * 4096 + ldsb);                      \
    }                                                                             \
  } while (0)

  f32x4 acc[4][4];
#pragma unroll
  for (int i = 0; i < 4; ++i)
#pragma unroll
    for (int j = 0; j < 4; ++j) acc[i][j] = (f32x4){0.f, 0.f, 0.f, 0.f};

  int cur = 0;
  GSTAGE(0, 0);
  for (int ks = 0; ks < 32; ++ks) {
    GSTAGE(cur ^ 1, (ks + 1) & 31);
    asm volatile("s_waitcnt vmcnt(4)" ::: "memory");
    __builtin_amdgcn_s_barrier();
    __builtin_amdgcn_sched_barrier(0);
    const char* Ac = (const char*)A_lds + cur * 8192;
    const char* Bc = (const char*)B_lds + cur * 8192;
    bf16x8 af[4], bfr[4];
#pragma unroll
    for (int i = 0; i < 4; ++i) {
      int row = wr * 64 + i * 16 + c;
      af[i] = *(const bf16x8*)(Ac + row * 64 + ((g * 16) ^ ((row & 3) << 4)));
    }
#pragma unroll
    for (int j = 0; j < 4; ++j) {
      int row = wc * 64 + j * 16 + c;
      bfr[j] = *(const bf16x8*)(Bc + row * 64 + ((g * 16) ^ ((row & 3) << 4)));
    }
    __builtin_amdgcn_s_setprio(1);
#pragma unroll
    for (int i = 0; i < 4; ++i)
#pragma unroll
      for (int j = 0; j < 4; ++j)
        acc[i][j] = __builtin_amdgcn_mfma_f32_16x16x32_bf16(af[i], bfr[j], acc[i][j], 0, 0, 0);
    __builtin_amdgcn_s_setprio(0);
    asm volatile("s_waitcnt lgkmcnt(0)" ::: "memory");
    __builtin_amdgcn_s_barrier();
    __builtin_amdgcn_sched_barrier(0);
    cur ^= 1;
  }
#undef GSTAGE

  const int sec = n0 >> 10;  // block-uniform: 0=Q, 1=K, 2=V
  if (sec < 2) {
#pragma unroll
    for (int i = 0; i < 4; ++i)
#pragma unroll
      for (int j = 0; j < 4; ++j)
#pragma unroll
        for (int r = 0; r < 4; ++r) {
          int m = m0 + wr * 64 + i * 16 + g * 4 + r;
          int cc = (n0 + wc * 64 + j * 16 + c) & 1023;
          u16 v = f2bf(acc[i][j][r]);
          if (sec == 0) Qb[(size_t)m * 1024 + cc] = v;
          else Kb[(size_t)m * 1024 + cc] = v;
        }
  } else {
    // V^T via LDS transpose (loop's final barrier already synced; SH is free).
    const int gq = ((g & 1) << 1) | (g >> 1);  // quad-swap 1<->2 for V n-order
    const int cc0 = n0 & 1023;
#pragma unroll
    for (int i = 0; i < 4; ++i)
#pragma unroll
      for (int j = 0; j < 4; ++j)
#pragma unroll
        for (int r = 0; r < 4; ++r) {
          int cl = wc * 64 + j * 16 + c;            // local col (d)
          int mql = wr * 64 + i * 16 + gq * 4 + r;  // local n, quad-interleaved
          SH[cl * 128 + (mql ^ ((cl & 15) << 3))] = f2bf(acc[i][j][r]);
        }
    __syncthreads();
#pragma unroll
    for (int p = 0; p < 4; ++p) {
      int row = p * 32 + (tid >> 3);
#pragma unroll
      for (int half = 0; half < 2; ++half) {
        int mq = (tid & 7) * 8 + half * 64;
        bf16x8 vv = *(const bf16x8*)&SH[row * 128 + (mq ^ ((row & 15) << 3))];
        *(bf16x8*)(Vth + (size_t)(cc0 + row) * 4096 + m0 + mq) = vv;
      }
    }
  }
}

// ---------------- out-proj GEMM, 128x64 tiles: out[4096][1024] = A @ Wot^T + bo ----------------
__global__ __launch_bounds__(256) void gemm_out128(const u16* __restrict__ A,
                                                   const u16* __restrict__ Bt,
                                                   float* __restrict__ out,
                                                   const float* __restrict__ bias) {
  __shared__ __align__(16) u16 A_lds[2][128 * 32];
  __shared__ __align__(16) u16 B_lds[2][64 * 32];
  const int tid = threadIdx.x;
  const int l = tid & 63, w = tid >> 6;
  const int g = l >> 4, c = l & 15;
  const int m0 = blockIdx.y * 128, n0 = blockIdx.x * 64;

  const int srow = tid >> 2;
  const u32 sswz = (u32)(((tid & 3) * 16) ^ ((srow & 3) << 4));
  const char* Ag = (const char*)A + (size_t)(m0 + srow) * 2048 + sswz;
  const char* Bg = (const char*)Bt + (size_t)(n0 + srow) * 2048 + sswz;
  const u32 ldsb = (u32)(w * 1024);

#define GSTAGE3(buf, ks_)                                                         \
  do {                                                                            \
    u32 koff_ = (u32)(ks_) * 64;                                                  \
    GLD16(Ag + koff_, (char*)A_lds[buf] + ldsb);                                  \
    GLD16(Ag + koff_ + (size_t)64 * 2048, (char*)A_lds[buf] + 4096 + ldsb);       \
    GLD16(Bg + koff_, (char*)B_lds[buf] + ldsb);                                  \
  } while (0)

  f32x4 acc[2][4];
#pragma unroll
  for (int i = 0; i < 2; ++i)
#pragma unroll
    for (int j = 0; j < 4; ++j) acc[i][j] = (f32x4){0.f, 0.f, 0.f, 0.f};

  int cur = 0;
  GSTAGE3(0, 0);
  for (int ks = 0; ks < 32; ++ks) {
    GSTAGE3(cur ^ 1, (ks + 1) & 31);
    asm volatile("s_waitcnt vmcnt(3)" ::: "memory");
    __builtin_amdgcn_s_barrier();
    __builtin_amdgcn_sched_barrier(0);
    const char* Ac = (const char*)A_lds[cur];
    const char* Bc = (const char*)B_lds[cur];
    bf16x8 af[2], bfr[4];
#pragma unroll
    for (int i = 0; i < 2; ++i) {
      int row = w * 32 + i * 16 + c;
      af[i] = *(const bf16x8*)(Ac + row * 64 + ((g * 16) ^ ((row & 3) << 4)));
    }
#pragma unroll
    for (int j = 0; j < 4; ++j) {
      int row = j * 16 + c;
      bfr[j] = *(const bf16x8*)(Bc + row * 64 + ((g * 16) ^ ((row & 3) << 4)));
    }
    __builtin_amdgcn_s_setprio(1);
#pragma unroll
    for (int i = 0; i < 2; ++i)
#pragma unroll
      for (int j = 0; j < 4; ++j)
        acc[i][j] = __builtin_amdgcn_mfma_f32_16x16x32_bf16(af[i], bfr[j], acc[i][j], 0, 0, 0);
    __builtin_amdgcn_s_setprio(0);
    asm volatile("s_waitcnt lgkmcnt(0)" ::: "memory");
    __builtin_amdgcn_s_barrier();
    __builtin_amdgcn_sched_barrier(0);
    cur ^= 1;
  }
#undef GSTAGE3

#pragma unroll
  for (int i = 0; i < 2; ++i)
#pragma unroll
    for (int j = 0; j < 4; ++j)
#pragma unroll
      for (int r = 0; r < 4; ++r) {
        int m = m0 + w * 32 + i * 16 + g * 4 + r;
        int col = n0 + j * 16 + c;
        out[(size_t)m * 1024 + col] = acc[i][j][r] + bias[col];
      }
}

// ---------------- flash attention, swapped-QK^T 32x32, no-max exp2 softmax ----------------
// ROUND-10-EXACT structure (proven 85.3 us): double-buffered K/V, TWO barriers per
// KV tile (vmcnt(4)+barrier pre-compute; lgkmcnt(0)+barrier post-compute).
// 64 q-rows per wave (two 32-row groups). Early-softmax P-carry across the stagger.
template <int SPLIT>
__global__ __launch_bounds__(256, 2) void flash_attn_t(const u16* __restrict__ Qb,
                                                       const u16* __restrict__ Kb,
                                                       const u16* __restrict__ Vt,
                                                       u16* __restrict__ Ob,
                                                       float* __restrict__ Op,
                                                       float* __restrict__ Lp) {
  constexpr int NT = SPLIT ? 32 : 64;  // KV tiles per block
  __shared__ __align__(16) u16 K_lds[2][64 * 64];
  __shared__ __align__(16) u16 V_lds[2][64 * 64];
  const int tid = threadIdx.x;
  const int l = tid & 63, w = tid >> 6;
  const int lq = l & 31, hi = l >> 5;
  const int h = blockIdx.y;
  const int z = SPLIT ? blockIdx.z : 0;
  const int kb = z * 32;                      // KV tile base (split half)
  const int qb = blockIdx.x * 256 + w * 64;   // wave's 64-row q base
  const int q0 = qb + lq, q1 = qb + 32 + lq;

  bf16x8 qf0[4], qf1[4];
  {
    const u16* qr0 = Qb + (size_t)q0 * 1024 + h * 64;
    const u16* qr1 = Qb + (size_t)q1 * 1024 + h * 64;
#pragma unroll
    for (int dm = 0; dm < 4; ++dm) {
      qf0[dm] = *(const bf16x8*)(qr0 + dm * 16 + hi * 8);
      qf1[dm] = *(const bf16x8*)(qr1 + dm * 16 + hi * 8);
    }
  }

  f32x16 ot0[2], ot1[2];
#pragma unroll
  for (int a = 0; a < 2; ++a)
#pragma unroll
    for (int r = 0; r < 16; ++r) { ot0[a][r] = 0.f; ot1[a][r] = 0.f; }
  float lrow0 = 0.f, lrow1 = 0.f;
  u32 pkA0[16], pkA1[16], pkB0[16], pkB1[16];

  const int srow = tid >> 3;
  const u32 sswz = (u32)(((tid & 7) * 16) ^ ((srow & 7) << 4));
  const char* Kg = (const char*)Kb + ((size_t)srow * 1024 + h * 64) * 2 + sswz;
  const char* Vg = (const char*)Vt + ((size_t)(h * 64 + srow) * 4096) * 2 + sswz;
  const u32 ldsb = (u32)(w * 1024);

  // PV only: each V fragment read once, feeds both q-groups' accumulators
#define PVONLY(P0, P1, VSLOT)                                                     \
  {                                                                               \
    const char* Vp_ = (const char*)(VSLOT);                                       \
    __builtin_amdgcn_s_setprio(1);                                                \
    _Pragma("unroll") for (int sti_ = 0; sti_ < 4; ++sti_) {                      \
      u32x4 pw0_ = {P0[sti_ * 4 + 0], P0[sti_ * 4 + 1], P0[sti_ * 4 + 2],         \
                    P0[sti_ * 4 + 3]};                                            \
      u32x4 pw1_ = {P1[sti_ * 4 + 0], P1[sti_ * 4 + 1], P1[sti_ * 4 + 2],         \
                    P1[sti_ * 4 + 3]};                                            \
      bf16x8 pf0_ = __builtin_bit_cast(bf16x8, pw0_);                             \
      bf16x8 pf1_ = __builtin_bit_cast(bf16x8, pw1_);                             \
      const u32 cb_ = (u32)(sti_ * 32 + hi * 16);                                 \
      _Pragma("unroll") for (int a_ = 0; a_ < 2; ++a_) {                          \
        const int rowd_ = a_ * 32 + lq;                                           \
        const u32 rs_ = (u32)(rowd_ * 128), rz_ = (u32)((rowd_ & 7) << 4);        \
        bf16x8 vf_ = *(const bf16x8*)(Vp_ + rs_ + (cb_ ^ rz_));                   \
        ot0[a_] = __builtin_amdgcn_mfma_f32_32x32x16_bf16(vf_, pf0_, ot0[a_], 0, 0, 0); \
        ot1[a_] = __builtin_amdgcn_mfma_f32_32x32x16_bf16(vf_, pf1_, ot1[a_], 0, 0, 0); \
      }                                                                           \
    }                                                                             \
    __builtin_amdgcn_s_setprio(0);                                                \
  }

  // BODY: stage K(TI+1),V(TI); QK(TI) both groups (kf shared); PV(TI-1); softmax->pk
#define BODY(TI, C0, C1, P0, P1, DOPREV)                                          \
  {                                                                               \
    const int ti_ = (TI);                                                         \
    const int nxt_ = (ti_ + 1) & (NT - 1);                                        \
    {                                                                             \
      const char* kg_ = Kg + (size_t)(kb + nxt_) * 64 * 2048;                     \
      char* kl_ = (char*)K_lds[nxt_ & 1] + ldsb;                                  \
      GLD16(kg_, kl_);                                                            \
      GLD16(kg_ + 32 * 2048, kl_ + 4096);                                         \
      const char* vg_ = Vg + (size_t)(kb + ti_) * 128;                            \
      char* vl_ = (char*)V_lds[ti_ & 1] + ldsb;                                   \
      GLD16(vg_, vl_);                                                            \
      GLD16(vg_ + (size_t)32 * 8192, vl_ + 4096);                                 \
    }                                                                             \
    asm volatile("s_waitcnt vmcnt(4)" ::: "memory");                              \
    __builtin_amdgcn_s_barrier();                                                 \
    __builtin_amdgcn_sched_barrier(0);                                            \
    const char* Kc_ = (const char*)K_lds[ti_ & 1];                                \
    f32x16 st0_[2], st1_[2];                                                      \
    _Pragma("unroll") for (int s_ = 0; s_ < 2; ++s_)                              \
    _Pragma("unroll") for (int r_ = 0; r_ < 16; ++r_) {                           \
      st0_[s_][r_] = 0.f;                                                         \
      st1_[s_][r_] = 0.f;                                                         \
    }                                                                             \
    __builtin_amdgcn_s_setprio(1);                                                \
    _Pragma("unroll") for (int s_ = 0; s_ < 2; ++s_) {                            \
      const int row_ = s_ * 32 + lq;                                              \
      const u32 rs_ = (u32)(row_ * 128), rz_ = (u32)((row_ & 7) << 4);            \
      _Pragma("unroll") for (int dm_ = 0; dm_ < 4; ++dm_) {                       \
        bf16x8 kf_ = *(const bf16x8*)(Kc_ + rs_ + ((u32)(dm_ * 32 + hi * 16) ^ rz_)); \
        st0_[s_] = __builtin_amdgcn_mfma_f32_32x32x16_bf16(kf_, qf0[dm_], st0_[s_], 0, 0, 0); \
        st1_[s_] = __builtin_amdgcn_mfma_f32_32x32x16_bf16(kf_, qf1[dm_], st1_[s_], 0, 0, 0); \
      }                                                                           \
    }                                                                             \
    __builtin_amdgcn_s_setprio(0);                                                \
    if (DOPREV) PVONLY(P0, P1, V_lds[(ti_ - 1) & 1]);                             \
    float rs0_ = 0.f, rs1_ = 0.f;                                                 \
    _Pragma("unroll") for (int s_ = 0; s_ < 2; ++s_)                              \
    _Pragma("unroll") for (int j_ = 0; j_ < 8; ++j_) {                            \
      float a0_ = __builtin_amdgcn_exp2f(st0_[s_][2 * j_]);                       \
      float a1_ = __builtin_amdgcn_exp2f(st0_[s_][2 * j_ + 1]);                   \
      rs0_ += a0_ + a1_;                                                          \
      u32 wp0_;                                                                   \
      asm("v_cvt_pk_bf16_f32 %0, %1, %2" : "=v"(wp0_) : "v"(a0_), "v"(a1_));      \
      C0[s_ * 8 + j_] = wp0_;                                                     \
      float b0_ = __builtin_amdgcn_exp2f(st1_[s_][2 * j_]);                       \
      float b1_ = __builtin_amdgcn_exp2f(st1_[s_][2 * j_ + 1]);                   \
      rs1_ += b0_ + b1_;                                                          \
      u32 wp1_;                                                                   \
      asm("v_cvt_pk_bf16_f32 %0, %1, %2" : "=v"(wp1_) : "v"(b0_), "v"(b1_));      \
      C1[s_ * 8 + j_] = wp1_;                                                     \
    }                                                                             \
    lrow0 += rs0_;                                                                \
    lrow1 += rs1_;                                                                \
    asm volatile("s_waitcnt lgkmcnt(0)" ::: "memory");                            \
    __builtin_amdgcn_s_barrier();                                                 \
    __builtin_amdgcn_sched_barrier(0);                                            \
  }

  {  // prologue: stage K(kb)
    const char* kg0 = Kg + (size_t)kb * 64 * 2048;
    char* kl = (char*)K_lds[0] + ldsb;
    GLD16(kg0, kl);
    GLD16(kg0 + 32 * 2048, kl + 4096);
  }

  BODY(0, pkA0, pkA1, pkA0, pkA1, 0);
  for (int i = 1; i < NT - 1; i += 2) {
    BODY(i, pkB0, pkB1, pkA0, pkA1, 1);
    BODY(i + 1, pkA0, pkA1, pkB0, pkB1, 1);
  }
  BODY(NT - 1, pkB0, pkB1, pkA0, pkA1, 1);
  asm volatile("s_waitcnt vmcnt(0)" ::: "memory");
  __builtin_amdgcn_s_barrier();
  __builtin_amdgcn_sched_barrier(0);
  PVONLY(pkB0, pkB1, V_lds[(NT - 1) & 1]);

#undef BODY
#undef PVONLY

  lrow0 += __shfl_xor(lrow0, 32, 64);
  lrow1 += __shfl_xor(lrow1, 32, 64);
  if constexpr (SPLIT) {
    float* or0 = Op + (size_t)z * (4096 * 1024) + (size_t)q0 * 1024 + h * 64 + hi * 4;
    float* or1 = Op + (size_t)z * (4096 * 1024) + (size_t)q1 * 1024 + h * 64 + hi * 4;
#pragma unroll
    for (int a = 0; a < 2; ++a)
#pragma unroll
      for (int rr = 0; rr < 4; ++rr) {
        float4 f0 = {ot0[a][rr * 4 + 0], ot0[a][rr * 4 + 1], ot0[a][rr * 4 + 2],
                     ot0[a][rr * 4 + 3]};
        *(float4*)(or0 + a * 32 + rr * 8) = f0;
        float4 f1 = {ot1[a][rr * 4 + 0], ot1[a][rr * 4 + 1], ot1[a][rr * 4 + 2],
                     ot1[a][rr * 4 + 3]};
        *(float4*)(or1 + a * 32 + rr * 8) = f1;
      }
    if (hi == 0) {
      Lp[z * 65536 + h * 4096 + q0] = lrow0;
      Lp[z * 65536 + h * 4096 + q1] = lrow1;
    }
  } else {
    float inv0 = 1.f / lrow0, inv1 = 1.f / lrow1;
    u16* or0 = Ob + (size_t)q0 * 1024 + h * 64 + hi * 4;
    u16* or1 = Ob + (size_t)q1 * 1024 + h * 64 + hi * 4;
#pragma unroll
    for (int a = 0; a < 2; ++a)
#pragma unroll
      for (int rr = 0; rr < 4; ++rr) {
        ushort4 o4;
        o4.x = f2bf(ot0[a][rr * 4 + 0] * inv0);
        o4.y = f2bf(ot0[a][rr * 4 + 1] * inv0);
        o4.z = f2bf(ot0[a][rr * 4 + 2] * inv0);
        o4.w = f2bf(ot0[a][rr * 4 + 3] * inv0);
        *(ushort4*)(or0 + a * 32 + rr * 8) = o4;
        o4.x = f2bf(ot1[a][rr * 4 + 0] * inv1);
        o4.y = f2bf(ot1[a][rr * 4 + 1] * inv1);
        o4.z = f2bf(ot1[a][rr * 4 + 2] * inv1);
        o4.w = f2bf(ot1[a][rr * 4 + 3] * inv1);
        *(ushort4*)(or1 + a * 32 + rr * 8) = o4;
      }
  }
}

// ---------------- merge KV halves: Ob = (O0+O1)/(L0+L1), f32 -> bf16 ----------------
__global__ __launch_bounds__(256) void merge_halves(const float* __restrict__ O0,
                                                    const float* __restrict__ O1,
                                                    const float* __restrict__ L0,
                                                    const float* __restrict__ L1,
                                                    u16* __restrict__ Ob) {
  int idx = blockIdx.x * 256 + threadIdx.x;  // 8 cols each
  int q = idx >> 7;
  int c0 = (idx & 127) * 8;
  int h = c0 >> 6;
  float inv = 1.f / (L0[h * 4096 + q] + L1[h * 4096 + q]);
  size_t off = (size_t)q * 1024 + c0;
  float4 a0 = *(const float4*)(O0 + off), a1 = *(const float4*)(O0 + off + 4);
  float4 b0 = *(const float4*)(O1 + off), b1 = *(const float4*)(O1 + off + 4);
  ushort4 o0, o1;
  o0.x = f2bf((a0.x + b0.x) * inv);
  o0.y = f2bf((a0.y + b0.y) * inv);
  o0.z = f2bf((a0.z + b0.z) * inv);
  o0.w = f2bf((a0.w + b0.w) * inv);
  o1.x = f2bf((a1.x + b1.x) * inv);
  o1.y = f2bf((a1.y + b1.y) * inv);
  o1.z = f2bf((a1.z + b1.z) * inv);
  o1.w = f2bf((a1.w + b1.w) * inv);
  *(ushort4*)(Ob + off) = o0;
  *(ushort4*)(Ob + off + 4) = o1;
}

extern "C" void kernel_launch(void* const* d_in, const int* in_sizes, int n_in,
                              void* d_out, int out_size, void* d_ws, size_t ws_size,
                              hipStream_t stream) {
  const float* x = (const float*)d_in[0];
  const float* Wq = (const float*)d_in[1];
  const float* Wk = (const float*)d_in[2];
  const float* Wv = (const float*)d_in[3];
  const float* Wo = (const float*)d_in[4];
  const float* bo = (const float*)d_in[5];
  float* out = (float*)d_out;

  char* ws = (char*)d_ws;
  u16* xb  = (u16*)(ws);                  // 8 MB (dead after gemm_qkv; reused as ObM)
  u16* Wqt = (u16*)(ws + (8u << 20));     // 2 MB  [Wqt|Wkt|Wvt] contiguous
  u16* Wot = (u16*)(ws + (14u << 20));    // 2 MB
  u16* Qb  = (u16*)(ws + (16u << 20));    // 8 MB
  u16* Kbf = (u16*)(ws + (24u << 20));    // 8 MB
  u16* Vth = (u16*)(ws + (32u << 20));    // 8 MB  [h][64][n] (quad-interleaved n)
  u16* Ob  = (u16*)(ws + (40u << 20));    // 8 MB (fallback path output)
  float* Op = (float*)(ws + (40u << 20)); // 32 MB (split path: 2x f32 partials)
  float* Lp = (float*)(ws + (72u << 20)); // 512 KB (2x16x4096 f32)
  u16* Wkt = Wqt + (1u << 20);
  u16* Wvt = Wqt + (2u << 20);

  const bool split = ws_size >= ((73u << 20) + (1u << 19));

  prep<<<dim3(16, 16, 6), 256, 0, stream>>>(x, Wq, Wk, Wv, Wo, xb, Wqt, Wkt, Wvt, Wot);
  gemm_qkv<<<dim3(24, 32), 256, 0, stream>>>(xb, Wqt, Qb, Kbf, Vth);

  if (split) {
    flash_attn_t<1><<<dim3(16, 16, 2), 256, 0, stream>>>(Qb, Kbf, Vth, nullptr, Op, Lp);
    u16* ObM = (u16*)ws;  // reuse xb region
    merge_halves<<<2048, 256, 0, stream>>>(Op, Op + (1u << 22), Lp, Lp + 65536, ObM);
    gemm_out128<<<dim3(16, 32), 256, 0, stream>>>(ObM, Wot, out, bo);
  } else {
    flash_attn_t<0><<<dim3(16, 16, 1), 256, 0, stream>>>(Qb, Kbf, Vth, Ob, nullptr, nullptr);
    gemm_out128<<<dim3(16, 32), 256, 0, stream>>>(Ob, Wot, out, bo);
  }
}